// Round 1
// baseline (514.573 us; speedup 1.0000x reference)
//
#include <hip/hip_runtime.h>
#include <hip/hip_bf16.h>

typedef unsigned int u32;
typedef unsigned long long u64;

// ---------------- Threefry-2x32 (20 rounds), exact JAX semantics ----------------
__host__ __device__ __forceinline__ void tf2x32(u32 k0, u32 k1, u32 x0, u32 x1,
                                                u32& o0, u32& o1)
{
    const u32 ks2 = k0 ^ k1 ^ 0x1BD11BDAu;
    x0 += k0; x1 += k1;
#define TF_R(r) { x0 += x1; x1 = (x1 << (r)) | (x1 >> (32 - (r))); x1 ^= x0; }
    TF_R(13) TF_R(15) TF_R(26) TF_R(6)
    x0 += k1; x1 += ks2 + 1u;
    TF_R(17) TF_R(29) TF_R(16) TF_R(24)
    x0 += ks2; x1 += k0 + 2u;
    TF_R(13) TF_R(15) TF_R(26) TF_R(6)
    x0 += k0; x1 += k1 + 3u;
    TF_R(17) TF_R(29) TF_R(16) TF_R(24)
    x0 += k1; x1 += ks2 + 4u;
    TF_R(13) TF_R(15) TF_R(26) TF_R(6)
    x0 += ks2; x1 += k0 + 5u;
#undef TF_R
    o0 = x0; o1 = x1;
}

// partitionable random_bits for 32-bit: counter = (hi=0, lo=e), bits = o0 ^ o1
__device__ __forceinline__ u32 rbits(u32 k0, u32 k1, u32 e)
{
    u32 o0, o1; tf2x32(k0, k1, 0u, e, o0, o1); return o0 ^ o1;
}

#define HW        262144u      // 512*512 = 2^18
#define PMASK     262143u
#define KEEP      183500u      // int(262144*0.7)
#define NX        50331648u    // 64*3*512*512
#define NM        16777216u    // 64*512*512
#define LO_F      (-0.99999994039535522461f)   // nextafter(-1,0), = -(1-2^-24)

__device__ __forceinline__ float noise_from_bits(u32 bits)
{
    float f  = __uint_as_float((bits >> 9) | 0x3F800000u) - 1.0f;   // [0,1)
    float un = fmaf(f, 2.0f, LO_F);          // maxval-minval rounds to exactly 2.0f
    un = fmaxf(LO_F, un);
    // Giles single-precision erfinv (same construction as XLA's ErfInv f32)
    float w = -__logf(fmaf(-un, un, 1.0f));
    float p;
    if (w < 5.0f) {
        w -= 2.5f;
        p = 2.81022636e-08f;
        p = fmaf(p, w, 3.43273939e-07f);
        p = fmaf(p, w, -3.5233877e-06f);
        p = fmaf(p, w, -4.39150654e-06f);
        p = fmaf(p, w, 0.00021858087f);
        p = fmaf(p, w, -0.00125372503f);
        p = fmaf(p, w, -0.00417768164f);
        p = fmaf(p, w, 0.246640727f);
        p = fmaf(p, w, 1.50140941f);
    } else {
        w = __fsqrt_rn(w) - 3.0f;
        p = -0.000200214257f;
        p = fmaf(p, w, 0.000100950558f);
        p = fmaf(p, w, 0.00134934322f);
        p = fmaf(p, w, -0.00367342844f);
        p = fmaf(p, w, 0.00573950773f);
        p = fmaf(p, w, -0.0076224613f);
        p = fmaf(p, w, 0.00943887047f);
        p = fmaf(p, w, 1.00167406f);
        p = fmaf(p, w, 2.83297682f);
    }
    float ei = p * un;                         // erfinv(un)
    return fmaf(1.41421356f * ei, 0.1f, 1.0f); // 1 + NOISE_STD * sqrt(2)*erfinv
}

// K1: generate mask m=bits>>9 for all 16.7M pixels, store, coarse hist (m>>11).
// 1024 blocks x 256 thr; block covers 16384 consecutive elements, one row each.
__global__ __launch_bounds__(256) void k1_gen_hist(u32 mk0, u32 mk1, u32* mbuf, u32* hist)
{
    __shared__ u32 lh[4096];
    const int t = threadIdx.x;
    const u32 blk = blockIdx.x;
    const u32 row = blk >> 4;
    const u32 base = blk << 14;
#pragma unroll
    for (int i = 0; i < 16; ++i) lh[t + (i << 8)] = 0;
    __syncthreads();
    uint4* mv = (uint4*)mbuf;
#pragma unroll 1
    for (int i = 0; i < 16; ++i) {
        u32 vi = (u32)(i << 8) + (u32)t;
        u32 e = base + (vi << 2);
        uint4 q;
        q.x = rbits(mk0, mk1, e)     >> 9;
        q.y = rbits(mk0, mk1, e + 1) >> 9;
        q.z = rbits(mk0, mk1, e + 2) >> 9;
        q.w = rbits(mk0, mk1, e + 3) >> 9;
        mv[(base >> 2) + vi] = q;
        atomicAdd(&lh[q.x >> 11], 1u);
        atomicAdd(&lh[q.y >> 11], 1u);
        atomicAdd(&lh[q.z >> 11], 1u);
        atomicAdd(&lh[q.w >> 11], 1u);
    }
    __syncthreads();
    u32* gh = hist + (row << 12);
#pragma unroll
    for (int i = 0; i < 16; ++i) {
        u32 idx = (u32)t + (i << 8);
        u32 v = lh[idx];
        if (v) atomicAdd(&gh[idx], v);
    }
}

// find smallest bin with cumulative >= k, over 256*PER bins. sh needs 258 u32.
template <int PER>
__device__ __forceinline__ void rank_scan(const u32* h, u32 k, u32* sh, u32& bin, u32& rem)
{
    const int t = threadIdx.x;   // 256 threads
    u32 v[PER]; u32 s = 0;
#pragma unroll
    for (int i = 0; i < PER; ++i) { v[i] = h[t * PER + i]; s += v[i]; }
    sh[t] = s;
    __syncthreads();
    if (t == 0) {
        u32 run = 0; u32 c = 0;
        for (; c < 255u; ++c) { u32 cs = sh[c]; if (run + cs >= k) break; run += cs; }
        sh[256] = c; sh[257] = run;
    }
    __syncthreads();
    u32 c = sh[256];
    if (t == (int)c) {
        u32 run = sh[257];
        u32 b = (u32)t * PER + PER - 1; u32 r = k - run;
#pragma unroll
        for (int i = 0; i < PER; ++i) {
            if (run + v[i] >= k) { b = (u32)t * PER + i; r = k - run; break; }
            run += v[i];
        }
        sh[256] = b; sh[257] = r;
    }
    __syncthreads();
    bin = sh[256]; rem = sh[257];
    __syncthreads();
}

// K2b: coarse-bin select per row + fine histogram (m & 2047) of that bin.
__global__ __launch_bounds__(256) void k2b_finehist(const u32* mbuf, const u32* hist,
                                                    u32* fhist, u32* rowBr)
{
    __shared__ u32 sh[258];
    __shared__ u32 fh[2048];
    const int t = threadIdx.x;
    const u32 blk = blockIdx.x;     // 1024
    const u32 row = blk >> 4;
    u32 B, r;
    rank_scan<16>(hist + (row << 12), KEEP, sh, B, r);
    if ((blk & 15u) == 0 && t == 0) { rowBr[row * 2] = B; rowBr[row * 2 + 1] = r; }
#pragma unroll
    for (int i = 0; i < 8; ++i) fh[t + (i << 8)] = 0;
    __syncthreads();
    const uint4* mv = (const uint4*)mbuf + (blk << 12);
#pragma unroll 1
    for (int i = 0; i < 16; ++i) {
        uint4 q = mv[(i << 8) + t];
        if ((q.x >> 11) == B) atomicAdd(&fh[q.x & 2047u], 1u);
        if ((q.y >> 11) == B) atomicAdd(&fh[q.y & 2047u], 1u);
        if ((q.z >> 11) == B) atomicAdd(&fh[q.z & 2047u], 1u);
        if ((q.w >> 11) == B) atomicAdd(&fh[q.w & 2047u], 1u);
    }
    __syncthreads();
    u32* gf = fhist + (row << 11);
#pragma unroll
    for (int i = 0; i < 8; ++i) {
        u32 idx = (u32)t + (i << 8);
        u32 v = fh[idx];
        if (v) atomicAdd(&gf[idx], v);
    }
}

// K2d: fine select -> m*, r2; collect tie pixel indices (m == m*).
__global__ __launch_bounds__(256) void k2d_ties(const u32* mbuf, const u32* fhist,
                                                const u32* rowBr, u32* rowM,
                                                u32* tiecnt, u32* tielist)
{
    __shared__ u32 sh[258];
    const int t = threadIdx.x;
    const u32 blk = blockIdx.x;     // 1024
    const u32 row = blk >> 4;
    u32 r = rowBr[row * 2 + 1];
    u32 B = rowBr[row * 2];
    u32 f, r2;
    rank_scan<8>(fhist + (row << 11), r, sh, f, r2);
    u32 mstar = (B << 11) | f;
    if ((blk & 15u) == 0 && t == 0) { rowM[row * 2] = mstar; rowM[row * 2 + 1] = r2; }
    const uint4* mv = (const uint4*)mbuf + (blk << 12);
#pragma unroll 1
    for (int i = 0; i < 16; ++i) {
        u32 vi = (u32)(i << 8) + (u32)t;
        uint4 q = mv[vi];
        u32 p = ((blk & 15u) << 14) + (vi << 2);
        if (q.x == mstar) { u32 pos = atomicAdd(&tiecnt[row], 1u); if (pos < 256u) tielist[(row << 8) + pos] = p; }
        if (q.y == mstar) { u32 pos = atomicAdd(&tiecnt[row], 1u); if (pos < 256u) tielist[(row << 8) + pos] = p + 1; }
        if (q.z == mstar) { u32 pos = atomicAdd(&tiecnt[row], 1u); if (pos < 256u) tielist[(row << 8) + pos] = p + 2; }
        if (q.w == mstar) { u32 pos = atomicAdd(&tiecnt[row], 1u); if (pos < 256u) tielist[(row << 8) + pos] = p + 3; }
    }
}

// K2e: per row, pick r2-th smallest tie index -> K* = (m*<<18)|p*
__global__ __launch_bounds__(64) void k2e_select(const u32* rowM, const u32* tiecnt,
                                                 const u32* tielist, u64* rowsel)
{
    __shared__ u32 list[256];
    const int t = threadIdx.x;       // 64
    const u32 row = blockIdx.x;      // 64
    u32 mstar = rowM[row * 2], r2 = rowM[row * 2 + 1];
    u32 cnt = tiecnt[row]; if (cnt > 256u) cnt = 256u;
    for (u32 i = (u32)t; i < cnt; i += 64u) list[i] = tielist[(row << 8) + i];
    __syncthreads();
    if (t == 0) {
        if (r2 > cnt) r2 = cnt;
        u32 pstar = 0;
        for (u32 it = 0; it < r2; ++it) {
            u32 mn = 0xFFFFFFFFu, mi = 0;
            for (u32 i2 = 0; i2 < cnt; ++i2) if (list[i2] < mn) { mn = list[i2]; mi = i2; }
            pstar = mn; list[mi] = 0xFFFFFFFFu;
        }
        rowsel[row] = ((u64)mstar << 18) | (u64)pstar;
    }
}

// K3: in-place transform m -> mask float (K = (m<<18)|p  <=  K*row).
__global__ __launch_bounds__(256) void k3_mask(u32* mbuf, const u64* rowsel)
{
    u32 tid = blockIdx.x * 256u + threadIdx.x;    // 4194304 (uint4 units)
    u32 row = tid >> 16;
    u64 kst = rowsel[row];
    uint4 q = ((const uint4*)mbuf)[tid];
    u32 p = (tid << 2) & PMASK;
    float4 o;
    o.x = ((((u64)q.x << 18) | (u64)(p))     <= kst) ? 1.0f : 0.0f;
    o.y = ((((u64)q.y << 18) | (u64)(p + 1)) <= kst) ? 1.0f : 0.0f;
    o.z = ((((u64)q.z << 18) | (u64)(p + 2)) <= kst) ? 1.0f : 0.0f;
    o.w = ((((u64)q.w << 18) | (u64)(p + 3)) <= kst) ? 1.0f : 0.0f;
    ((float4*)mbuf)[tid] = o;
}

// K4: out = x * mask * noise, 4 elements/thread.
__global__ __launch_bounds__(256) void k4_final(const float4* x4, const float* maskf,
                                                float4* out4, u32 nk0, u32 nk1)
{
    u32 tid = blockIdx.x * 256u + threadIdx.x;    // 12582912
    u32 e = tid << 2;
    u32 b = e / 786432u;                          // 3*2^18
    u32 p = e & PMASK;                            // valid: c*2^18 aligned
    float4 mk = *(const float4*)(maskf + ((b << 18) | p));
    float4 xv = x4[tid];
    float4 r;
    r.x = (xv.x * mk.x) * noise_from_bits(rbits(nk0, nk1, e));
    r.y = (xv.y * mk.y) * noise_from_bits(rbits(nk0, nk1, e + 1));
    r.z = (xv.z * mk.z) * noise_from_bits(rbits(nk0, nk1, e + 2));
    r.w = (xv.w * mk.w) * noise_from_bits(rbits(nk0, nk1, e + 3));
    out4[tid] = r;
}

extern "C" void kernel_launch(void* const* d_in, const int* in_sizes, int n_in,
                              void* d_out, int out_size, void* d_ws, size_t ws_size,
                              hipStream_t stream) {
    const float* x = (const float*)d_in[0];
    float* xout = (float*)d_out;                  // 50331648 floats
    u32*  outu = (u32*)d_out;
    u32*  mbuf = (u32*)(xout + NX);               // mask region: m then mask floats

    // scratch inside x-region (overwritten last by k4)
    u32* hist    = outu;                          // 64*4096
    u32* fhist   = outu + 262144;                 // 64*2048
    u32* tiecnt  = outu + 393216;                 // 64
    u32* tielist = outu + 393472;                 // 64*256
    u32* rowBr   = outu + 409856;                 // 64*2
    u32* rowM    = outu + 410112;                 // 64*2
    u64* rowsel  = (u64*)(outu + 410368);         // 64 u64 (8B aligned)

    // host: fold-like split of key(42): k_mask = TF(0,42,0,0), k_noise = TF(0,42,0,1)
    u32 mk0, mk1, nk0, nk1;
    tf2x32(0u, 42u, 0u, 0u, mk0, mk1);
    tf2x32(0u, 42u, 0u, 1u, nk0, nk1);

    hipMemsetAsync(hist, 0, (262144u + 131072u + 64u) * sizeof(u32), stream);
    k1_gen_hist<<<1024, 256, 0, stream>>>(mk0, mk1, mbuf, hist);
    k2b_finehist<<<1024, 256, 0, stream>>>(mbuf, hist, fhist, rowBr);
    k2d_ties<<<1024, 256, 0, stream>>>(mbuf, fhist, rowBr, rowM, tiecnt, tielist);
    k2e_select<<<64, 64, 0, stream>>>(rowM, tiecnt, tielist, rowsel);
    k3_mask<<<16384, 256, 0, stream>>>(mbuf, rowsel);
    k4_final<<<49152, 256, 0, stream>>>((const float4*)x, (const float*)mbuf,
                                        (float4*)xout, nk0, nk1);
    (void)d_ws; (void)ws_size; (void)in_sizes; (void)n_in; (void)out_size;
}